// Round 1
// baseline (130.149 us; speedup 1.0000x reference)
//
#include <hip/hip_runtime.h>
#include <hip/hip_bf16.h>

// dce_loss: dist[b,i] = sum_d sigma[i,d]*(x[b,d]-centers[i,d])^2
// out = concat(centers, sigma, -dist)
// -dist[b,i] = sum_d [ (-sigma)[i,d]*x2[b,d] + (2*sigma*centers)[i,d]*x[b,d] ]
//              - sum_d sigma[i,d]*centers[i,d]^2
// => bf16 GEMM: A[8192][2048] = [x^2 | x],  W[2048][2048] = [-sigma | 2*sigma*c]
//    (both K-contiguous, i.e. A * W^T), + f32 per-column constant.

#define B_SZ 8192
#define C_SZ 2048
#define D_SZ 1024
#define K2   2048   // 2*D_SZ

typedef __attribute__((ext_vector_type(4))) float f32x4;
typedef __attribute__((ext_vector_type(8))) short bf16x8;

static __device__ __forceinline__ unsigned short f2bf(float f) {
  union { float f; unsigned int u; } v; v.f = f;
  unsigned int r = v.u + 0x7fffu + ((v.u >> 16) & 1u);   // RNE, finite inputs
  return (unsigned short)(r >> 16);
}

// ---- preprocess: A = [bf16(x^2) | bf16(x)] ----------------------------------
__global__ __launch_bounds__(256) void build_a(const float* __restrict__ x,
                                               unsigned short* __restrict__ Aop) {
  const long t = (long)blockIdx.x * 256 + threadIdx.x;   // one per 8 elems
  const long e = t * 8;
  const long b = e >> 10;          // row (D=1024 per row)
  const int  d = (int)(e & 1023);
  const float4* xv = (const float4*)x;
  float4 v0 = xv[2 * t], v1 = xv[2 * t + 1];
  float vs[8] = {v0.x, v0.y, v0.z, v0.w, v1.x, v1.y, v1.z, v1.w};
  unsigned short sq[8] __attribute__((aligned(16)));
  unsigned short rw[8] __attribute__((aligned(16)));
#pragma unroll
  for (int j = 0; j < 8; ++j) {
    rw[j] = f2bf(vs[j]);
    sq[j] = f2bf(vs[j] * vs[j]);
  }
  *(uint4*)(Aop + b * K2 + d)        = *(uint4*)sq;
  *(uint4*)(Aop + b * K2 + D_SZ + d) = *(uint4*)rw;
}

// ---- preprocess: W = [bf16(-sigma) | bf16(2*sigma*centers)] -----------------
__global__ __launch_bounds__(256) void build_w(const float* __restrict__ centers,
                                               const float* __restrict__ sigma,
                                               unsigned short* __restrict__ Wop) {
  const long t = (long)blockIdx.x * 256 + threadIdx.x;
  const long e = t * 8;
  const long i = e >> 10;
  const int  d = (int)(e & 1023);
  const float4* cv = (const float4*)centers;
  const float4* sv = (const float4*)sigma;
  float4 c0 = cv[2 * t], c1 = cv[2 * t + 1];
  float4 s0 = sv[2 * t], s1 = sv[2 * t + 1];
  float cs[8] = {c0.x, c0.y, c0.z, c0.w, c1.x, c1.y, c1.z, c1.w};
  float ss[8] = {s0.x, s0.y, s0.z, s0.w, s1.x, s1.y, s1.z, s1.w};
  unsigned short w1[8] __attribute__((aligned(16)));
  unsigned short w2[8] __attribute__((aligned(16)));
#pragma unroll
  for (int j = 0; j < 8; ++j) {
    w1[j] = f2bf(-ss[j]);
    w2[j] = f2bf(2.0f * ss[j] * cs[j]);
  }
  *(uint4*)(Wop + i * K2 + d)        = *(uint4*)w1;
  *(uint4*)(Wop + i * K2 + D_SZ + d) = *(uint4*)w2;
}

// ---- preprocess: cn[i] = -sum_d sigma[i,d]*centers[i,d]^2 (exact f32) -------
__global__ __launch_bounds__(256) void build_c(const float* __restrict__ centers,
                                               const float* __restrict__ sigma,
                                               float* __restrict__ cn) {
  const long i = blockIdx.x;
  float4 c = ((const float4*)(centers + i * D_SZ))[threadIdx.x];
  float4 s = ((const float4*)(sigma   + i * D_SZ))[threadIdx.x];
  float p = s.x * c.x * c.x + s.y * c.y * c.y + s.z * c.z * c.z + s.w * c.w * c.w;
#pragma unroll
  for (int off = 32; off > 0; off >>= 1) p += __shfl_down(p, off, 64);
  __shared__ float red[4];
  if ((threadIdx.x & 63) == 0) red[threadIdx.x >> 6] = p;
  __syncthreads();
  if (threadIdx.x == 0) cn[i] = -(red[0] + red[1] + red[2] + red[3]);
}

// ---- GEMM: out[b][i] = A[b][:] . W[i][:] + cn[i] ----------------------------
// m97 structure: 128x128 tile, BK=64, 4 waves (2x2 of 64x64), single LDS buf,
// global_load_lds width 16, ds_read_b128 fragments, mfma 16x16x32 bf16.
__global__ __launch_bounds__(256) void gemm_bt(const unsigned short* __restrict__ A,
                                               const unsigned short* __restrict__ W,
                                               const float* __restrict__ cn,
                                               float* __restrict__ out) {
  __shared__ __attribute__((aligned(16))) unsigned short As[128 * 64];
  __shared__ __attribute__((aligned(16))) unsigned short Bs[128 * 64];

  const int tid  = threadIdx.x;
  const int lane = tid & 63;
  const int wave = tid >> 6;
  const int wr = wave >> 1;      // 0..1
  const int wc = wave & 1;       // 0..1

  const long rowBase = (long)blockIdx.y * 128;   // M tile (b)
  const long colBase = (long)blockIdx.x * 128;   // N tile (class i)

  // staging: each thread loads 4x 16B for A and for W per K-step
  const int e0 = tid * 8;              // element in 128x64 tile
  const int sr = e0 >> 6;              // 0..31 (+32 per it)
  const int sc = e0 & 63;
  const unsigned short* aSrc = A + (rowBase + sr) * K2 + sc;
  const unsigned short* wSrc = W + (colBase + sr) * K2 + sc;

  f32x4 acc[4][4];
  const f32x4 zero = {0.0f, 0.0f, 0.0f, 0.0f};
#pragma unroll
  for (int i = 0; i < 4; ++i)
#pragma unroll
    for (int j = 0; j < 4; ++j) acc[i][j] = zero;

  for (int k0 = 0; k0 < K2; k0 += 64) {
    __syncthreads();   // previous compute done before overwriting LDS
#pragma unroll
    for (int it = 0; it < 4; ++it) {
      __builtin_amdgcn_global_load_lds(
          (__attribute__((address_space(1))) void*)(aSrc + k0 + (long)it * 32 * K2),
          (__attribute__((address_space(3))) void*)(As + e0 + it * 2048), 16, 0, 0);
      __builtin_amdgcn_global_load_lds(
          (__attribute__((address_space(1))) void*)(wSrc + k0 + (long)it * 32 * K2),
          (__attribute__((address_space(3))) void*)(Bs + e0 + it * 2048), 16, 0, 0);
    }
    __syncthreads();   // compiler drains vmcnt before barrier -> tiles ready

#pragma unroll
    for (int kk = 0; kk < 2; ++kk) {
      const int kofs = kk * 32 + (lane >> 4) * 8;
      bf16x8 af[4], bw[4];
#pragma unroll
      for (int mi = 0; mi < 4; ++mi)
        af[mi] = *(const bf16x8*)(As + (wr * 64 + mi * 16 + (lane & 15)) * 64 + kofs);
#pragma unroll
      for (int ni = 0; ni < 4; ++ni)
        bw[ni] = *(const bf16x8*)(Bs + (wc * 64 + ni * 16 + (lane & 15)) * 64 + kofs);
#pragma unroll
      for (int mi = 0; mi < 4; ++mi)
#pragma unroll
        for (int ni = 0; ni < 4; ++ni)
          acc[mi][ni] = __builtin_amdgcn_mfma_f32_16x16x32_bf16(
              af[mi], bw[ni], acc[mi][ni], 0, 0, 0);
    }
  }

  // epilogue: C/D layout col=lane&15, row=(lane>>4)*4+j  (m89-verified)
  const int crow = (lane >> 4) * 4;
  const int ccol = lane & 15;
#pragma unroll
  for (int ni = 0; ni < 4; ++ni) {
    const long col = colBase + wc * 64 + ni * 16 + ccol;
    const float c = cn[col];
#pragma unroll
    for (int mi = 0; mi < 4; ++mi) {
      const long row = rowBase + wr * 64 + mi * 16 + crow;
      float* o = out + row * C_SZ + col;
#pragma unroll
      for (int j = 0; j < 4; ++j) o[(long)j * C_SZ] = acc[mi][ni][j] + c;
    }
  }
}

extern "C" void kernel_launch(void* const* d_in, const int* in_sizes, int n_in,
                              void* d_out, int out_size, void* d_ws, size_t ws_size,
                              hipStream_t stream) {
  const float* x       = (const float*)d_in[0];
  const float* centers = (const float*)d_in[1];
  const float* sigma   = (const float*)d_in[2];
  float* out = (float*)d_out;

  unsigned short* Aop = (unsigned short*)d_ws;            // 8192*2048 bf16 = 33.5 MB
  unsigned short* Wop = Aop + (long)B_SZ * K2;            // 2048*2048 bf16 = 8.4 MB
  float* cn = (float*)(Wop + (long)C_SZ * K2);            // 2048 f32

  // outputs 0/1: exact copies
  hipMemcpyAsync(out, centers, (size_t)C_SZ * D_SZ * sizeof(float),
                 hipMemcpyDeviceToDevice, stream);
  hipMemcpyAsync(out + (size_t)C_SZ * D_SZ, sigma, (size_t)C_SZ * D_SZ * sizeof(float),
                 hipMemcpyDeviceToDevice, stream);

  build_a<<<B_SZ * D_SZ / 8 / 256, 256, 0, stream>>>(x, Aop);
  build_w<<<C_SZ * D_SZ / 8 / 256, 256, 0, stream>>>(centers, sigma, Wop);
  build_c<<<C_SZ, 256, 0, stream>>>(centers, sigma, cn);

  float* out2 = out + (size_t)2 * C_SZ * D_SZ;
  dim3 grid(C_SZ / 128, B_SZ / 128);   // (N tiles, M tiles) = (16, 64)
  gemm_bt<<<grid, 256, 0, stream>>>(Aop, Wop, cn, out2);
}

// Round 2
// 100.769 us; speedup vs baseline: 1.2915x; 1.2915x over previous
//
#include <hip/hip_runtime.h>
#include <hip/hip_bf16.h>

// dce_loss: out = concat(centers, sigma, -dist)
// -dist[b,i] = sum_k A[b,k]*W[i,k] + cn[i],  A=[bf16(x^2)|bf16(x)], W=[-sigma|2*sigma*c]
// GEMM: 256x256 tile, BK=32, 8 waves, 3-buffer LDS ring, counted vmcnt(4),
// 2 phases/K-tile of 16 MFMA each (T2+T3+T4+T5 per 8-phase template).

#define B_SZ 8192
#define C_SZ 2048
#define D_SZ 1024
#define K2   2048

typedef __attribute__((ext_vector_type(4))) float f32x4;
typedef __attribute__((ext_vector_type(8))) short bf16x8;

static __device__ __forceinline__ unsigned short f2bf(float f) {
  union { float f; unsigned int u; } v; v.f = f;
  unsigned int r = v.u + 0x7fffu + ((v.u >> 16) & 1u);   // RNE, finite inputs
  return (unsigned short)(r >> 16);
}

// ---- preprocess: A = [bf16(x^2) | bf16(x)] ----------------------------------
__global__ __launch_bounds__(256) void build_a(const float* __restrict__ x,
                                               unsigned short* __restrict__ Aop) {
  const long t = (long)blockIdx.x * 256 + threadIdx.x;   // one per 8 elems
  const long e = t * 8;
  const long b = e >> 10;
  const int  d = (int)(e & 1023);
  const float4* xv = (const float4*)x;
  float4 v0 = xv[2 * t], v1 = xv[2 * t + 1];
  float vs[8] = {v0.x, v0.y, v0.z, v0.w, v1.x, v1.y, v1.z, v1.w};
  unsigned short sq[8] __attribute__((aligned(16)));
  unsigned short rw[8] __attribute__((aligned(16)));
#pragma unroll
  for (int j = 0; j < 8; ++j) {
    rw[j] = f2bf(vs[j]);
    sq[j] = f2bf(vs[j] * vs[j]);
  }
  *(uint4*)(Aop + b * K2 + d)        = *(uint4*)sq;
  *(uint4*)(Aop + b * K2 + D_SZ + d) = *(uint4*)rw;
}

// ---- fused: output copies of centers/sigma + W build + cn reduction ---------
__global__ __launch_bounds__(128) void prep_w(const float* __restrict__ centers,
                                              const float* __restrict__ sigma,
                                              float* __restrict__ out_centers,
                                              float* __restrict__ out_sigma,
                                              unsigned short* __restrict__ Wop,
                                              float* __restrict__ cn) {
  const int i = blockIdx.x;          // class
  const int t = threadIdx.x;         // 0..127, 8 elems each
  const long base = (long)i * D_SZ;
  const float4* cv = (const float4*)(centers + base);
  const float4* sv = (const float4*)(sigma + base);
  float4 c0 = cv[2 * t], c1 = cv[2 * t + 1];
  float4 s0 = sv[2 * t], s1 = sv[2 * t + 1];
  ((float4*)(out_centers + base))[2 * t]     = c0;
  ((float4*)(out_centers + base))[2 * t + 1] = c1;
  ((float4*)(out_sigma + base))[2 * t]       = s0;
  ((float4*)(out_sigma + base))[2 * t + 1]   = s1;
  float cs[8] = {c0.x, c0.y, c0.z, c0.w, c1.x, c1.y, c1.z, c1.w};
  float ss[8] = {s0.x, s0.y, s0.z, s0.w, s1.x, s1.y, s1.z, s1.w};
  unsigned short w1[8] __attribute__((aligned(16)));
  unsigned short w2[8] __attribute__((aligned(16)));
  float p = 0.0f;
#pragma unroll
  for (int j = 0; j < 8; ++j) {
    w1[j] = f2bf(-ss[j]);
    w2[j] = f2bf(2.0f * ss[j] * cs[j]);
    p += ss[j] * cs[j] * cs[j];
  }
  *(uint4*)(Wop + (long)i * K2 + t * 8)        = *(uint4*)w1;
  *(uint4*)(Wop + (long)i * K2 + D_SZ + t * 8) = *(uint4*)w2;
#pragma unroll
  for (int off = 32; off > 0; off >>= 1) p += __shfl_down(p, off, 64);
  __shared__ float red[2];
  if ((t & 63) == 0) red[t >> 6] = p;
  __syncthreads();
  if (t == 0) cn[i] = -(red[0] + red[1]);
}

// ---- GEMM 256x256, BK=32, 3-buffer ring, phase-split schedule ---------------
#define NOVM() ((void)0)
#define VM4()  asm volatile("s_waitcnt vmcnt(4)" ::: "memory")
#define VM0()  asm volatile("s_waitcnt vmcnt(0)" ::: "memory")
#define LGKM0() asm volatile("s_waitcnt lgkmcnt(0)" ::: "memory")
#define SB()   __builtin_amdgcn_sched_barrier(0)
#define BAR()  __builtin_amdgcn_s_barrier()

// stage half H (128 rows) of K-tile KT into ring buffer BUFI (linear dest;
// source k-slot pre-swizzled so swizzled reads see logical data)
#define STAGE_H(KT, BUFI, H)                                                     \
  do {                                                                           \
    __builtin_amdgcn_global_load_lds(                                            \
        (__attribute__((address_space(1))) void*)(aS + (long)(H) * 128 * K2 + (long)(KT) * 32), \
        (__attribute__((address_space(3))) void*)(&As[BUFI][(H) * 4096 + dstE]), \
        16, 0, 0);                                                               \
    __builtin_amdgcn_global_load_lds(                                            \
        (__attribute__((address_space(1))) void*)(bS + (long)(H) * 128 * K2 + (long)(KT) * 32), \
        (__attribute__((address_space(3))) void*)(&Bs[BUFI][(H) * 4096 + dstE]), \
        16, 0, 0);                                                               \
  } while (0)

#define MFMA16(P)                                                                              \
  acc[(P)*4+0][0] = __builtin_amdgcn_mfma_f32_16x16x32_bf16(af0, bw0, acc[(P)*4+0][0], 0,0,0); \
  acc[(P)*4+0][1] = __builtin_amdgcn_mfma_f32_16x16x32_bf16(af0, bw1, acc[(P)*4+0][1], 0,0,0); \
  acc[(P)*4+0][2] = __builtin_amdgcn_mfma_f32_16x16x32_bf16(af0, bw2, acc[(P)*4+0][2], 0,0,0); \
  acc[(P)*4+0][3] = __builtin_amdgcn_mfma_f32_16x16x32_bf16(af0, bw3, acc[(P)*4+0][3], 0,0,0); \
  acc[(P)*4+1][0] = __builtin_amdgcn_mfma_f32_16x16x32_bf16(af1, bw0, acc[(P)*4+1][0], 0,0,0); \
  acc[(P)*4+1][1] = __builtin_amdgcn_mfma_f32_16x16x32_bf16(af1, bw1, acc[(P)*4+1][1], 0,0,0); \
  acc[(P)*4+1][2] = __builtin_amdgcn_mfma_f32_16x16x32_bf16(af1, bw2, acc[(P)*4+1][2], 0,0,0); \
  acc[(P)*4+1][3] = __builtin_amdgcn_mfma_f32_16x16x32_bf16(af1, bw3, acc[(P)*4+1][3], 0,0,0); \
  acc[(P)*4+2][0] = __builtin_amdgcn_mfma_f32_16x16x32_bf16(af2, bw0, acc[(P)*4+2][0], 0,0,0); \
  acc[(P)*4+2][1] = __builtin_amdgcn_mfma_f32_16x16x32_bf16(af2, bw1, acc[(P)*4+2][1], 0,0,0); \
  acc[(P)*4+2][2] = __builtin_amdgcn_mfma_f32_16x16x32_bf16(af2, bw2, acc[(P)*4+2][2], 0,0,0); \
  acc[(P)*4+2][3] = __builtin_amdgcn_mfma_f32_16x16x32_bf16(af2, bw3, acc[(P)*4+2][3], 0,0,0); \
  acc[(P)*4+3][0] = __builtin_amdgcn_mfma_f32_16x16x32_bf16(af3, bw0, acc[(P)*4+3][0], 0,0,0); \
  acc[(P)*4+3][1] = __builtin_amdgcn_mfma_f32_16x16x32_bf16(af3, bw1, acc[(P)*4+3][1], 0,0,0); \
  acc[(P)*4+3][2] = __builtin_amdgcn_mfma_f32_16x16x32_bf16(af3, bw2, acc[(P)*4+3][2], 0,0,0); \
  acc[(P)*4+3][3] = __builtin_amdgcn_mfma_f32_16x16x32_bf16(af3, bw3, acc[(P)*4+3][3], 0,0,0);

#define PHASE(BUFI, P, STG, KTS, SBUFI, BND)                                   \
  do {                                                                         \
    bf16x8 af0 = *(const bf16x8*)(&As[BUFI][aBase + (P) * 2048 + 0]);          \
    bf16x8 af1 = *(const bf16x8*)(&As[BUFI][aBase + (P) * 2048 + 512]);        \
    bf16x8 af2 = *(const bf16x8*)(&As[BUFI][aBase + (P) * 2048 + 1024]);       \
    bf16x8 af3 = *(const bf16x8*)(&As[BUFI][aBase + (P) * 2048 + 1536]);       \
    if (P == 0) {                                                              \
      bw0 = *(const bf16x8*)(&Bs[BUFI][bBase + 0]);                            \
      bw1 = *(const bf16x8*)(&Bs[BUFI][bBase + 512]);                          \
      bw2 = *(const bf16x8*)(&Bs[BUFI][bBase + 1024]);                         \
      bw3 = *(const bf16x8*)(&Bs[BUFI][bBase + 1536]);                         \
    }                                                                          \
    if (STG) { STAGE_H(KTS, SBUFI, P); }                                       \
    SB(); BAR(); LGKM0(); SB();                                                \
    __builtin_amdgcn_s_setprio(1);                                             \
    MFMA16(P)                                                                  \
    __builtin_amdgcn_s_setprio(0);                                             \
    BND();                                                                     \
    SB(); BAR(); SB();                                                         \
  } while (0)

#define KTILE(BUFI, STG, KTS, SBUFI, BND)                                      \
  do {                                                                         \
    PHASE(BUFI, 0, STG, KTS, SBUFI, NOVM);                                     \
    PHASE(BUFI, 1, STG, KTS, SBUFI, BND);                                      \
  } while (0)

__global__ __launch_bounds__(512, 2) void gemm256(const unsigned short* __restrict__ A,
                                                  const unsigned short* __restrict__ W,
                                                  const float* __restrict__ cn,
                                                  float* __restrict__ out) {
  __shared__ __attribute__((aligned(16))) unsigned short As[3][8192];  // 3 x 256x32
  __shared__ __attribute__((aligned(16))) unsigned short Bs[3][8192];

  const int tid  = threadIdx.x;          // 0..511, 8 waves
  const int lane = tid & 63;
  const int wave = tid >> 6;
  const int wr = wave >> 2;              // 0..1  -> 128-row half
  const int wc = wave & 3;               // 0..3  -> 64-col slice

  const long rowBase = (long)blockIdx.y * 256;
  const long colBase = (long)blockIdx.x * 256;

  // staging: thread -> (row, 16B slot); source slot pre-swizzled (slot ^ row&3)
  const int sRow  = tid >> 2;                       // 0..127 within half
  const int sSlot = (tid & 3) ^ (sRow & 3);
  const unsigned short* aS = A + (rowBase + sRow) * K2 + sSlot * 8;
  const unsigned short* bS = W + (colBase + sRow) * K2 + sSlot * 8;
  const int dstE = tid * 8;                         // linear LDS dest (elems)

  // fragment read offsets: row*32 + swizzled slot*8   (row&3 == lane&3)
  const int rslot = (((lane >> 4) ^ (lane & 3)) * 8);
  const int aBase = (wr * 128 + (lane & 15)) * 32 + rslot;
  const int bBase = (wc * 64 + (lane & 15)) * 32 + rslot;

  f32x4 acc[8][4];
#pragma unroll
  for (int i = 0; i < 8; ++i)
#pragma unroll
    for (int j = 0; j < 4; ++j) acc[i][j] = (f32x4){0.f, 0.f, 0.f, 0.f};

  bf16x8 bw0, bw1, bw2, bw3;

  // prologue: stage KT0 -> buf0, KT1 -> buf1; wait KT0 (leave KT1 in flight)
  STAGE_H(0, 0, 0); STAGE_H(0, 0, 1);
  STAGE_H(1, 1, 0); STAGE_H(1, 1, 1);
  VM4(); SB(); BAR(); SB();

  // main: K-tile t from buf[t%3], stage t+2 into buf[(t+2)%3], vmcnt(4) boundary
#pragma unroll 1
  for (int t = 0; t < 60; t += 3) {
    KTILE(0, 1, t + 2, 2, VM4);
    KTILE(1, 1, t + 3, 0, VM4);
    KTILE(2, 1, t + 4, 1, VM4);
  }
  KTILE(0, 1, 62, 2, VM4);   // KT60, stage 62
  KTILE(1, 1, 63, 0, VM4);   // KT61, stage 63
  KTILE(2, 0, 0, 0, VM0);    // KT62, drain all (KT63 lands)
  KTILE(0, 0, 0, 0, NOVM);   // KT63

  // epilogue: C/D layout col=lane&15, row=(lane>>4)*4+j (m89-verified)
  const int crow = (lane >> 4) * 4;
  const int ccol = lane & 15;
#pragma unroll
  for (int ni = 0; ni < 4; ++ni) {
    const long col = colBase + wc * 64 + ni * 16 + ccol;
    const float c = cn[col];
#pragma unroll
    for (int mi = 0; mi < 8; ++mi) {
      const long row = rowBase + wr * 128 + mi * 16 + crow;
      float* o = out + row * C_SZ + col;
#pragma unroll
      for (int j = 0; j < 4; ++j) o[(long)j * C_SZ] = acc[mi][ni][j] + c;
    }
  }
}

extern "C" void kernel_launch(void* const* d_in, const int* in_sizes, int n_in,
                              void* d_out, int out_size, void* d_ws, size_t ws_size,
                              hipStream_t stream) {
  const float* x       = (const float*)d_in[0];
  const float* centers = (const float*)d_in[1];
  const float* sigma   = (const float*)d_in[2];
  float* out = (float*)d_out;

  unsigned short* Aop = (unsigned short*)d_ws;            // 8192*2048 bf16
  unsigned short* Wop = Aop + (long)B_SZ * K2;            // 2048*2048 bf16
  float* cnp = (float*)(Wop + (long)C_SZ * K2);           // 2048 f32

  build_a<<<B_SZ * D_SZ / 8 / 256, 256, 0, stream>>>(x, Aop);
  prep_w<<<C_SZ, 128, 0, stream>>>(centers, sigma,
                                   out, out + (size_t)C_SZ * D_SZ, Wop, cnp);

  float* out2 = out + (size_t)2 * C_SZ * D_SZ;
  dim3 grid(C_SZ / 256, B_SZ / 256);   // (8, 32) = 256 blocks = 1/CU
  gemm256<<<grid, 512, 0, stream>>>(Aop, Wop, cnp, out2);
}

// Round 3
// 86.688 us; speedup vs baseline: 1.5013x; 1.1624x over previous
//
#include <hip/hip_runtime.h>
#include <hip/hip_bf16.h>

// dce_loss: out = concat(centers, sigma, -dist)
// -dist[b,i] = sum_k A[b,k]*W[i,k] + cn[i],  A=[bf16(x^2)|bf16(x)], W=[-sigma|2*sigma*c]
// GEMM: 256x256 tile, BK=64, 8 waves, 2-buf LDS (128KB), 4 phases/K-tile,
// half-granular staging with counted vmcnt(4) (T2+T3+T4+T5), slot^=(row&7) swizzle.

#define B_SZ 8192
#define C_SZ 2048
#define D_SZ 1024
#define K2   2048
#define NT   32

typedef __attribute__((ext_vector_type(4))) float f32x4;
typedef __attribute__((ext_vector_type(8))) short bf16x8;

static __device__ __forceinline__ unsigned short f2bf(float f) {
  union { float f; unsigned int u; } v; v.f = f;
  unsigned int r = v.u + 0x7fffu + ((v.u >> 16) & 1u);   // RNE, finite inputs
  return (unsigned short)(r >> 16);
}

// ---- preprocess: A = [bf16(x^2) | bf16(x)] ----------------------------------
__global__ __launch_bounds__(256) void build_a(const float* __restrict__ x,
                                               unsigned short* __restrict__ Aop) {
  const long t = (long)blockIdx.x * 256 + threadIdx.x;
  const long e = t * 8;
  const long b = e >> 10;
  const int  d = (int)(e & 1023);
  const float4* xv = (const float4*)x;
  float4 v0 = xv[2 * t], v1 = xv[2 * t + 1];
  float vs[8] = {v0.x, v0.y, v0.z, v0.w, v1.x, v1.y, v1.z, v1.w};
  unsigned short sq[8] __attribute__((aligned(16)));
  unsigned short rw[8] __attribute__((aligned(16)));
#pragma unroll
  for (int j = 0; j < 8; ++j) {
    rw[j] = f2bf(vs[j]);
    sq[j] = f2bf(vs[j] * vs[j]);
  }
  *(uint4*)(Aop + b * K2 + d)        = *(uint4*)sq;
  *(uint4*)(Aop + b * K2 + D_SZ + d) = *(uint4*)rw;
}

// ---- fused: output copies of centers/sigma + W build + cn reduction ---------
__global__ __launch_bounds__(128) void prep_w(const float* __restrict__ centers,
                                              const float* __restrict__ sigma,
                                              float* __restrict__ out_centers,
                                              float* __restrict__ out_sigma,
                                              unsigned short* __restrict__ Wop,
                                              float* __restrict__ cn) {
  const int i = blockIdx.x;
  const int t = threadIdx.x;
  const long base = (long)i * D_SZ;
  const float4* cv = (const float4*)(centers + base);
  const float4* sv = (const float4*)(sigma + base);
  float4 c0 = cv[2 * t], c1 = cv[2 * t + 1];
  float4 s0 = sv[2 * t], s1 = sv[2 * t + 1];
  ((float4*)(out_centers + base))[2 * t]     = c0;
  ((float4*)(out_centers + base))[2 * t + 1] = c1;
  ((float4*)(out_sigma + base))[2 * t]       = s0;
  ((float4*)(out_sigma + base))[2 * t + 1]   = s1;
  float cs[8] = {c0.x, c0.y, c0.z, c0.w, c1.x, c1.y, c1.z, c1.w};
  float ss[8] = {s0.x, s0.y, s0.z, s0.w, s1.x, s1.y, s1.z, s1.w};
  unsigned short w1[8] __attribute__((aligned(16)));
  unsigned short w2[8] __attribute__((aligned(16)));
  float p = 0.0f;
#pragma unroll
  for (int j = 0; j < 8; ++j) {
    w1[j] = f2bf(-ss[j]);
    w2[j] = f2bf(2.0f * ss[j] * cs[j]);
    p += ss[j] * cs[j] * cs[j];
  }
  *(uint4*)(Wop + (long)i * K2 + t * 8)        = *(uint4*)w1;
  *(uint4*)(Wop + (long)i * K2 + D_SZ + t * 8) = *(uint4*)w2;
#pragma unroll
  for (int off = 32; off > 0; off >>= 1) p += __shfl_down(p, off, 64);
  __shared__ float red[2];
  if ((t & 63) == 0) red[t >> 6] = p;
  __syncthreads();
  if (t == 0) cn[i] = -(red[0] + red[1]);
}

// ---- GEMM -------------------------------------------------------------------
#define LGKM0() asm volatile("s_waitcnt lgkmcnt(0)" ::: "memory")
#define VM4()   asm volatile("s_waitcnt vmcnt(4)" ::: "memory")
#define VM0()   asm volatile("s_waitcnt vmcnt(0)" ::: "memory")
#define NOW()   ((void)0)
#define SB()    __builtin_amdgcn_sched_barrier(0)
#define BAR()   __builtin_amdgcn_s_barrier()

// stage half H (128 rows = 2 loads/thread) of K-tile KT into buf C
#define STAGE_A(C, H, KT)                                                       \
  do {                                                                          \
    __builtin_amdgcn_global_load_lds(                                           \
        (__attribute__((address_space(1))) void*)(aS + ((H)*128 + 0) * (long)K2 + (long)(KT)*64),  \
        (__attribute__((address_space(3))) void*)(&As[C][(H)*8192 + dstE]), 16, 0, 0);             \
    __builtin_amdgcn_global_load_lds(                                           \
        (__attribute__((address_space(1))) void*)(aS + ((H)*128 + 64) * (long)K2 + (long)(KT)*64), \
        (__attribute__((address_space(3))) void*)(&As[C][(H)*8192 + 4096 + dstE]), 16, 0, 0);      \
  } while (0)

#define STAGE_B(C, H, KT)                                                       \
  do {                                                                          \
    __builtin_amdgcn_global_load_lds(                                           \
        (__attribute__((address_space(1))) void*)(bS + ((H)*128 + 0) * (long)K2 + (long)(KT)*64),  \
        (__attribute__((address_space(3))) void*)(&Bs[C][(H)*8192 + dstE]), 16, 0, 0);             \
    __builtin_amdgcn_global_load_lds(                                           \
        (__attribute__((address_space(1))) void*)(bS + ((H)*128 + 64) * (long)K2 + (long)(KT)*64), \
        (__attribute__((address_space(3))) void*)(&Bs[C][(H)*8192 + 4096 + dstE]), 16, 0, 0);      \
  } while (0)

#define MM16(A0, A1, A2, A3, B0, B1, B2, B3, R)                                  \
  acc[(R)+0][0] = __builtin_amdgcn_mfma_f32_16x16x32_bf16(A0, B0, acc[(R)+0][0], 0,0,0); \
  acc[(R)+0][1] = __builtin_amdgcn_mfma_f32_16x16x32_bf16(A0, B1, acc[(R)+0][1], 0,0,0); \
  acc[(R)+0][2] = __builtin_amdgcn_mfma_f32_16x16x32_bf16(A0, B2, acc[(R)+0][2], 0,0,0); \
  acc[(R)+0][3] = __builtin_amdgcn_mfma_f32_16x16x32_bf16(A0, B3, acc[(R)+0][3], 0,0,0); \
  acc[(R)+1][0] = __builtin_amdgcn_mfma_f32_16x16x32_bf16(A1, B0, acc[(R)+1][0], 0,0,0); \
  acc[(R)+1][1] = __builtin_amdgcn_mfma_f32_16x16x32_bf16(A1, B1, acc[(R)+1][1], 0,0,0); \
  acc[(R)+1][2] = __builtin_amdgcn_mfma_f32_16x16x32_bf16(A1, B2, acc[(R)+1][2], 0,0,0); \
  acc[(R)+1][3] = __builtin_amdgcn_mfma_f32_16x16x32_bf16(A1, B3, acc[(R)+1][3], 0,0,0); \
  acc[(R)+2][0] = __builtin_amdgcn_mfma_f32_16x16x32_bf16(A2, B0, acc[(R)+2][0], 0,0,0); \
  acc[(R)+2][1] = __builtin_amdgcn_mfma_f32_16x16x32_bf16(A2, B1, acc[(R)+2][1], 0,0,0); \
  acc[(R)+2][2] = __builtin_amdgcn_mfma_f32_16x16x32_bf16(A2, B2, acc[(R)+2][2], 0,0,0); \
  acc[(R)+2][3] = __builtin_amdgcn_mfma_f32_16x16x32_bf16(A2, B3, acc[(R)+2][3], 0,0,0); \
  acc[(R)+3][0] = __builtin_amdgcn_mfma_f32_16x16x32_bf16(A3, B0, acc[(R)+3][0], 0,0,0); \
  acc[(R)+3][1] = __builtin_amdgcn_mfma_f32_16x16x32_bf16(A3, B1, acc[(R)+3][1], 0,0,0); \
  acc[(R)+3][2] = __builtin_amdgcn_mfma_f32_16x16x32_bf16(A3, B2, acc[(R)+3][2], 0,0,0); \
  acc[(R)+3][3] = __builtin_amdgcn_mfma_f32_16x16x32_bf16(A3, B3, acc[(R)+3][3], 0,0,0);

#define PH_TAIL()                                                              \
  SB(); BAR(); LGKM0(); SB(); __builtin_amdgcn_s_setprio(1)
#define PH_END()                                                               \
  __builtin_amdgcn_s_setprio(0); SB(); BAR()

// One K-tile U in buf C. Stages: ph0/ph1 -> A halves of U+1 (buf C^1),
// ph2/ph3 -> B halves of U+2 (buf C). Boundary wait BNDW at end of ph3.
#define TILE(C, U, STGA, STGB, BNDW)                                           \
  do {                                                                         \
    { /* ph0: A(kk0,mi0-3) x B(kk0) */                                         \
      bf16x8 a0 = *(const bf16x8*)(&As[C][aRd0 +    0]);                       \
      bf16x8 a1 = *(const bf16x8*)(&As[C][aRd0 + 1024]);                       \
      bf16x8 a2 = *(const bf16x8*)(&As[C][aRd0 + 2048]);                       \
      bf16x8 a3 = *(const bf16x8*)(&As[C][aRd0 + 3072]);                       \
      b00 = *(const bf16x8*)(&Bs[C][bRd0 +    0]);                             \
      b01 = *(const bf16x8*)(&Bs[C][bRd0 + 1024]);                             \
      b02 = *(const bf16x8*)(&Bs[C][bRd0 + 2048]);                             \
      b03 = *(const bf16x8*)(&Bs[C][bRd0 + 3072]);                             \
      if (STGA) STAGE_A((C)^1, 0, (U)+1);                                      \
      PH_TAIL();                                                               \
      MM16(a0, a1, a2, a3, b00, b01, b02, b03, 0)                              \
      PH_END();                                                                \
    }                                                                          \
    { /* ph1: A(kk0,mi4-7) x B(kk0); read B(kk1) */                            \
      bf16x8 a0 = *(const bf16x8*)(&As[C][aRd0 + 4096]);                       \
      bf16x8 a1 = *(const bf16x8*)(&As[C][aRd0 + 5120]);                       \
      bf16x8 a2 = *(const bf16x8*)(&As[C][aRd0 + 6144]);                       \
      bf16x8 a3 = *(const bf16x8*)(&As[C][aRd0 + 7168]);                       \
      b10 = *(const bf16x8*)(&Bs[C][bRd1 +    0]);                             \
      b11 = *(const bf16x8*)(&Bs[C][bRd1 + 1024]);                             \
      b12 = *(const bf16x8*)(&Bs[C][bRd1 + 2048]);                             \
      b13 = *(const bf16x8*)(&Bs[C][bRd1 + 3072]);                             \
      if (STGA) STAGE_A((C)^1, 1, (U)+1);                                      \
      PH_TAIL();                                                               \
      MM16(a0, a1, a2, a3, b00, b01, b02, b03, 4)                              \
      PH_END();                                                                \
    }                                                                          \
    { /* ph2: A(kk1,mi0-3) x B(kk1) */                                         \
      bf16x8 a0 = *(const bf16x8*)(&As[C][aRd1 +    0]);                       \
      bf16x8 a1 = *(const bf16x8*)(&As[C][aRd1 + 1024]);                       \
      bf16x8 a2 = *(const bf16x8*)(&As[C][aRd1 + 2048]);                       \
      bf16x8 a3 = *(const bf16x8*)(&As[C][aRd1 + 3072]);                       \
      if (STGB) STAGE_B((C), 0, (U)+2);                                        \
      PH_TAIL();                                                               \
      MM16(a0, a1, a2, a3, b10, b11, b12, b13, 0)                              \
      PH_END();                                                                \
    }                                                                          \
    { /* ph3: A(kk1,mi4-7) x B(kk1); boundary */                               \
      bf16x8 a0 = *(const bf16x8*)(&As[C][aRd1 + 4096]);                       \
      bf16x8 a1 = *(const bf16x8*)(&As[C][aRd1 + 5120]);                       \
      bf16x8 a2 = *(const bf16x8*)(&As[C][aRd1 + 6144]);                       \
      bf16x8 a3 = *(const bf16x8*)(&As[C][aRd1 + 7168]);                       \
      if (STGB) STAGE_B((C), 1, (U)+2);                                        \
      PH_TAIL();                                                               \
      MM16(a0, a1, a2, a3, b10, b11, b12, b13, 4)                              \
      __builtin_amdgcn_s_setprio(0);                                           \
      BNDW(); SB(); BAR();                                                     \
    }                                                                          \
  } while (0)

__global__ __launch_bounds__(512, 2) void gemm256(const unsigned short* __restrict__ A,
                                                  const unsigned short* __restrict__ W,
                                                  const float* __restrict__ cn,
                                                  float* __restrict__ out) {
  // LDS: [buf][256 rows][64 k] bf16, slot-swizzled (phys16Bslot = logical ^ (row&7))
  __shared__ __attribute__((aligned(16))) unsigned short As[2][16384];
  __shared__ __attribute__((aligned(16))) unsigned short Bs[2][16384];

  const int tid  = threadIdx.x;
  const int lane = tid & 63;
  const int wave = tid >> 6;
  const int wr = wave >> 2;              // 0..1 -> 128-row half of M
  const int wc = wave & 3;               // 0..3 -> 64-row slice of N

  // XCD-aware block swizzle: xcd owns 4 m-panels x 8 n-tiles (A panel L2-resident)
  const int bid = blockIdx.x;
  const int xcd = bid & 7, idx = bid >> 3;
  const long rowBase = (long)(xcd * 4 + (idx >> 3)) * 256;
  const long colBase = (long)(idx & 7) * 256;

  // staging: thread -> rows (tid>>3)+{0,64}, phys slot tid&7, logical = phys^(row&7)
  const int sr = tid >> 3;
  const int sl = (tid & 7) ^ (sr & 7);
  const unsigned short* aS = A + (rowBase + sr) * (long)K2 + sl * 8;
  const unsigned short* bS = W + (colBase + sr) * (long)K2 + sl * 8;
  const int dstE = tid * 8;

  // fragment reads: row = base + (lane&15), logical slot = kk*4 + (lane>>4)
  const int l15 = lane & 15, l7 = lane & 7, q = lane >> 4;
  const int ps0 = q ^ l7;           // phys slot, kk=0
  const int ps1 = ps0 ^ 4;          // phys slot, kk=1
  const int aRd0 = (wr * 128 + l15) * 64 + ps0 * 8;
  const int aRd1 = (wr * 128 + l15) * 64 + ps1 * 8;
  const int bRd0 = (wc * 64 + l15) * 64 + ps0 * 8;
  const int bRd1 = (wc * 64 + l15) * 64 + ps1 * 8;

  f32x4 acc[8][4];
#pragma unroll
  for (int i = 0; i < 8; ++i)
#pragma unroll
    for (int j = 0; j < 4; ++j) acc[i][j] = (f32x4){0.f, 0.f, 0.f, 0.f};

  bf16x8 b00, b01, b02, b03, b10, b11, b12, b13;

  // prologue: A(0),B(0)->buf0; B(1)->buf1; wait first 8 loads (leave B(1) in flight)
  STAGE_A(0, 0, 0); STAGE_A(0, 1, 0);
  STAGE_B(0, 0, 0); STAGE_B(0, 1, 0);
  STAGE_B(1, 0, 1); STAGE_B(1, 1, 1);
  VM4(); SB(); BAR();

#pragma unroll 1
  for (int u = 0; u < 28; u += 2) {
    TILE(0, u,     1, 1, VM4);
    TILE(1, u + 1, 1, 1, VM4);
  }
  TILE(0, 28, 1, 1, VM4);
  TILE(1, 29, 1, 1, VM4);   // stages A(30), B(31)
  TILE(0, 30, 1, 0, VM0);   // stages A(31); drain everything
  TILE(1, 31, 0, 0, NOW);

  // epilogue: C/D layout col=lane&15, row=(lane>>4)*4+j (m89-verified)
  const int crow = (lane >> 4) * 4;
  const int ccol = lane & 15;
#pragma unroll
  for (int ni = 0; ni < 4; ++ni) {
    const long col = colBase + wc * 64 + ni * 16 + ccol;
    const float c = cn[col];
#pragma unroll
    for (int mi = 0; mi < 8; ++mi) {
      const long row = rowBase + wr * 128 + mi * 16 + crow;
      float* o = out + row * C_SZ + col;
#pragma unroll
      for (int j = 0; j < 4; ++j) o[(long)j * C_SZ] = acc[mi][ni][j] + c;
    }
  }
}

extern "C" void kernel_launch(void* const* d_in, const int* in_sizes, int n_in,
                              void* d_out, int out_size, void* d_ws, size_t ws_size,
                              hipStream_t stream) {
  const float* x       = (const float*)d_in[0];
  const float* centers = (const float*)d_in[1];
  const float* sigma   = (const float*)d_in[2];
  float* out = (float*)d_out;

  unsigned short* Aop = (unsigned short*)d_ws;            // 8192*2048 bf16
  unsigned short* Wop = Aop + (long)B_SZ * K2;            // 2048*2048 bf16
  float* cnp = (float*)(Wop + (long)C_SZ * K2);           // 2048 f32

  build_a<<<B_SZ * D_SZ / 8 / 256, 256, 0, stream>>>(x, Aop);
  prep_w<<<C_SZ, 128, 0, stream>>>(centers, sigma,
                                   out, out + (size_t)C_SZ * D_SZ, Wop, cnp);

  float* out2 = out + (size_t)2 * C_SZ * D_SZ;
  gemm256<<<256, 512, 0, stream>>>(Aop, Wop, cnp, out2);
}